// Round 6
// baseline (422.610 us; speedup 1.0000x reference)
//
#include <hip/hip_runtime.h>

// C3-style layer via MFMA implicit GEMM, R5: sliding-window register reuse.
// x[32,6,512,512] f32 -> out[32,16,508,508] f32 (5x5 VALID conv; sparse
// oc<-ic connectivity via zero weights in dense [16,6,5,5] kernel).
//
// LDS tile T[col][slot][icp8] (f16, col pitch TR=21 uint4).  For output row d,
// K-chunk ch at tap kx is the 16B slice at uint4 slot g+ch*4+d of column
// px+kx (g = lane>>4).  Identity: frag(ch=1, d) == frag(ch=0, d+4)  ->
// ping-pong register banks cur/nxt[5][4] cut ds_read_b128 from 160 to 100
// per thread (the R4 bottleneck: 1 read per MFMA ~= 115us/CU issue time).

#define OW 508
#define BX 64     // output px per block; 4 waves x 16-px strips
#define BY 16     // output rows per block
#define TC 68     // T columns = BX + 4
#define TR 21     // uint4 slots per column (20 real rows + 1 zero row)
#define TPAD 4    // zeroed tail (over-reads at ky>=5 hit finite data; A=0 there)

typedef _Float16 h8 __attribute__((ext_vector_type(8)));
typedef _Float16 h2 __attribute__((ext_vector_type(2)));
typedef float f32x4 __attribute__((ext_vector_type(4)));

__device__ __constant__ int d_CH3[6][3] = {
    {0,1,2},{1,2,3},{2,3,4},{3,4,5},{0,4,5},{0,1,5}};
__device__ __constant__ int d_CH4[9][4] = {
    {0,1,2,3},{1,2,3,4},{2,3,4,5},{0,3,4,5},{0,1,4,5},
    {0,1,2,5},{0,1,3,4},{1,2,4,5},{0,2,3,5}};

// ws: bias f32[16] | AF ushort[5*2*64*8]
// AF[((kx*2+ch)*64 + lane)*8 + e]: weight for oc=lane&15, ky=ch*4+(lane>>4),
// ic=e, tap kx; zero if ky>=5 or e>=6.
__global__ void prep_weights(const float* __restrict__ w3, const float* __restrict__ b3,
                             const float* __restrict__ w4, const float* __restrict__ b4,
                             const float* __restrict__ w6, const float* __restrict__ b6,
                             float* __restrict__ bias, unsigned short* __restrict__ AF) {
    __shared__ float Wfull[16 * 6 * 25];   // dense [oc][ic][tap]
    const int tid = threadIdx.x;
    for (int i = tid; i < 16 * 6 * 25; i += 256) Wfull[i] = 0.f;
    __syncthreads();
    for (int i = tid; i < 6 * 3 * 25; i += 256) {
        int oc = i / 75, r = i % 75, c = r / 25, t = r % 25;
        Wfull[(oc * 6 + d_CH3[oc][c]) * 25 + t] = w3[i];
    }
    for (int i = tid; i < 9 * 4 * 25; i += 256) {
        int o = i / 100, r = i % 100, c = r / 25, t = r % 25;
        Wfull[((6 + o) * 6 + d_CH4[o][c]) * 25 + t] = w4[i];
    }
    for (int i = tid; i < 6 * 25; i += 256) Wfull[15 * 150 + i] = w6[i];
    __syncthreads();
    for (int i = tid; i < 5 * 2 * 64 * 8; i += 256) {
        int e = i & 7, lane = (i >> 3) & 63, ch = (i >> 9) & 1, kx = i >> 10;
        int oc = lane & 15, ky = ch * 4 + (lane >> 4);
        float w = 0.f;
        if (ky < 5 && e < 6) w = Wfull[(oc * 6 + e) * 25 + ky * 5 + kx];
        _Float16 hw = (_Float16)w;
        AF[i] = __builtin_bit_cast(unsigned short, hw);
    }
    if (tid < 6)        bias[tid] = b3[tid];
    else if (tid < 15)  bias[tid] = b4[tid - 6];
    else if (tid == 15) bias[tid] = b6[0];
}

// One group of 4 output rows d = 4*T .. 4*T+3.
// cur holds frag offsets {4T..4T+3}; loads nxt = offsets {4T+4..4T+7}.
template<int T>
__device__ __forceinline__ void conv_group(const uint4* __restrict__ Tb,
        const h8 (&afr)[10], const h8 (&cur)[5][4], h8 (&nxt)[5][4],
        f32x4 binit, float* __restrict__ out, size_t o00, int oy0, int px) {
    #pragma unroll
    for (int kx = 0; kx < 5; ++kx)
        #pragma unroll
        for (int i = 0; i < 4; ++i)
            nxt[kx][i] = *reinterpret_cast<const h8*>(&Tb[kx * TR + 4 * T + 4 + i]);

    #pragma unroll
    for (int i = 0; i < 4; ++i) {
        const int d = 4 * T + i;
        f32x4 acc = binit;
        #pragma unroll
        for (int kx = 0; kx < 5; ++kx) {
            acc = __builtin_amdgcn_mfma_f32_16x16x32_f16(afr[2 * kx + 0], cur[kx][i], acc, 0, 0, 0);
            acc = __builtin_amdgcn_mfma_f32_16x16x32_f16(afr[2 * kx + 1], nxt[kx][i], acc, 0, 0, 0);
        }
        const int oy = oy0 + d;
        if (oy < OW && px < OW) {
            const size_t cs = (size_t)OW * OW;
            size_t o0 = o00 + (size_t)d * OW;
            __builtin_nontemporal_store(acc.x, &out[o0]);
            __builtin_nontemporal_store(acc.y, &out[o0 + cs]);
            __builtin_nontemporal_store(acc.z, &out[o0 + 2 * cs]);
            __builtin_nontemporal_store(acc.w, &out[o0 + 3 * cs]);
        }
    }
}

__global__ __launch_bounds__(256) void conv_mfma(
        const float* __restrict__ x, const unsigned short* __restrict__ AF,
        const float* __restrict__ bias, float* __restrict__ out) {
    __shared__ uint4 T4[TC * TR + TPAD];   // 22912 B

    const int tid = threadIdx.x;
    const int gx0 = blockIdx.x * BX;
    const int oy0 = blockIdx.y * BY;
    const int bz  = blockIdx.z;
    const float* xb = x + (size_t)bz * 6 * 512 * 512;

    // ---- stage: word (c*84 + rr*4 + ip) = f16 pair (ic=2ip,2ip+1) at (c,rr)
    unsigned int* Tw = (unsigned int*)T4;
    for (int idx = tid; idx < TC * TR * 4 + TPAD * 4; idx += 256) {
        unsigned int val = 0u;
        int waddr = idx;
        if (idx < TC * TR * 4) {
            int c  = idx % TC;
            int rr = (idx / TC) % TR;
            int ip = idx / (TC * TR);      // 0..3 -> ic pair (2ip, 2ip+1)
            waddr = c * 84 + rr * 4 + ip;
            int gy = oy0 + rr, gx = gx0 + c;
            if (ip < 3 && rr < 20 && gy < 512 && gx < 512) {
                const float* p0 = xb + ((size_t)(2 * ip) * 512 + gy) * 512 + gx;
                float v0 = p0[0];
                float v1 = p0[262144];     // next ic plane
                h2 h; h.x = (_Float16)v0; h.y = (_Float16)v1;
                val = __builtin_bit_cast(unsigned int, h);
            }
        }
        Tw[waddr] = val;
    }
    __syncthreads();

    const int lane = tid & 63;
    const int n = lane & 15;        // B column = pixel within strip
    const int g = lane >> 4;        // k-group

    // A-fragments: 10 x 16 B per lane, coalesced, L2-resident
    h8 afr[10];
    #pragma unroll
    for (int q = 0; q < 10; ++q)
        afr[q] = *reinterpret_cast<const h8*>(AF + (q * 64 + lane) * 8);

    f32x4 binit;
    binit.x = bias[g * 4 + 0];
    binit.y = bias[g * 4 + 1];
    binit.z = bias[g * 4 + 2];
    binit.w = bias[g * 4 + 3];

    const int wstrip = tid >> 6;                 // 0..3
    const int col0   = wstrip * 16;
    const int px     = gx0 + col0 + n;           // output x
    const uint4* Tb  = &T4[(col0 + n) * TR + g]; // per-lane window base

    const size_t o00 = (((size_t)bz * 16 + g * 4) * OW + oy0) * OW + px;

    h8 BE[5][4], BO[5][4];
    #pragma unroll
    for (int kx = 0; kx < 5; ++kx)
        #pragma unroll
        for (int i = 0; i < 4; ++i)
            BE[kx][i] = *reinterpret_cast<const h8*>(&Tb[kx * TR + i]);

    conv_group<0>(Tb, afr, BE, BO, binit, out, o00, oy0, px);
    conv_group<1>(Tb, afr, BO, BE, binit, out, o00, oy0, px);
    conv_group<2>(Tb, afr, BE, BO, binit, out, o00, oy0, px);
    conv_group<3>(Tb, afr, BO, BE, binit, out, o00, oy0, px);
}

extern "C" void kernel_launch(void* const* d_in, const int* in_sizes, int n_in,
                              void* d_out, int out_size, void* d_ws, size_t ws_size,
                              hipStream_t stream) {
    const float* x  = (const float*)d_in[0];
    const float* w3 = (const float*)d_in[1];
    const float* b3 = (const float*)d_in[2];
    const float* w4 = (const float*)d_in[3];
    const float* b4 = (const float*)d_in[4];
    const float* w6 = (const float*)d_in[5];
    const float* b6 = (const float*)d_in[6];
    float* out = (float*)d_out;

    float* bias        = (float*)d_ws;                    // 16 f32
    unsigned short* AF = (unsigned short*)(bias + 16);    // 5120 u16

    prep_weights<<<1, 256, 0, stream>>>(w3, b3, w4, b4, w6, b6, bias, AF);

    dim3 grid((OW + BX - 1) / BX, (OW + BY - 1) / BY, 32);  // 8, 32, 32
    conv_mfma<<<grid, 256, 0, stream>>>(x, AF, bias, out);
}

// Round 7
// 295.031 us; speedup vs baseline: 1.4324x; 1.4324x over previous
//
#include <hip/hip_runtime.h>

// C3-style layer via MFMA implicit GEMM, R6: 32x32x16 MFMA, M = 2 rows x 16 oc.
// x[32,6,512,512] f32 -> out[32,16,508,508] f32 (5x5 VALID conv; sparse
// oc<-ic connectivity via zero weights in dense [16,6,5,5] kernel).
//
// GEMM view per kx: K = (window_row, icp8). A[m=(dy,oc)][k=(r,icp)] =
// W[oc][icp][ky=r-dy][kx] (zero outside 0<=ky<5 or icp>=6) -- independent of
// output row d.  B[k][n=px] = slice of LDS tile at uint4 slot d+r of column
// px+kx.  Per 2-row step: 5 kx x 3 K-chunks = 15 ds_read_b128 + 15 MFMA
// covering 32px x 2rows x 16oc = 1024 outputs -> LDS-read issue no longer
// the floor; HBM is (~790 MB).

#define OW 508
#define BX 128    // output px per block; 4 waves x 32-px strips
#define BY 16     // output rows per block
#define TC 132    // T columns = BX + 4
#define TR 21     // uint4 slots per column (20 rows; 21 keeps group-stride odd)

typedef _Float16 h8 __attribute__((ext_vector_type(8)));
typedef _Float16 h2 __attribute__((ext_vector_type(2)));
typedef float f32x16 __attribute__((ext_vector_type(16)));

__device__ __constant__ int d_CH3[6][3] = {
    {0,1,2},{1,2,3},{2,3,4},{3,4,5},{0,4,5},{0,1,5}};
__device__ __constant__ int d_CH4[9][4] = {
    {0,1,2,3},{1,2,3,4},{2,3,4,5},{0,3,4,5},{0,1,4,5},
    {0,1,2,5},{0,1,3,4},{1,2,4,5},{0,2,3,5}};

// ws: bias f32[16] | AF ushort[15*64*8]
// AF[((kx*3+ch)*64 + lane)*8 + e]: A-frag: oc=lane&15, dy=(lane>>4)&1,
// rr=lane>>5, r=ch*2+rr, ky=r-dy; value W[oc][e][ky][kx] or 0.
__global__ void prep_weights(const float* __restrict__ w3, const float* __restrict__ b3,
                             const float* __restrict__ w4, const float* __restrict__ b4,
                             const float* __restrict__ w6, const float* __restrict__ b6,
                             float* __restrict__ bias, unsigned short* __restrict__ AF) {
    __shared__ float Wfull[16 * 6 * 25];   // dense [oc][ic][tap]
    const int tid = threadIdx.x;
    for (int i = tid; i < 16 * 6 * 25; i += 256) Wfull[i] = 0.f;
    __syncthreads();
    for (int i = tid; i < 6 * 3 * 25; i += 256) {
        int oc = i / 75, r = i % 75, c = r / 25, t = r % 25;
        Wfull[(oc * 6 + d_CH3[oc][c]) * 25 + t] = w3[i];
    }
    for (int i = tid; i < 9 * 4 * 25; i += 256) {
        int o = i / 100, r = i % 100, c = r / 25, t = r % 25;
        Wfull[((6 + o) * 6 + d_CH4[o][c]) * 25 + t] = w4[i];
    }
    for (int i = tid; i < 6 * 25; i += 256) Wfull[15 * 150 + i] = w6[i];
    __syncthreads();
    for (int i = tid; i < 15 * 64 * 8; i += 256) {
        int e = i & 7, lane = (i >> 3) & 63, q = i >> 9;   // q = kx*3+ch
        int kx = q / 3, ch = q % 3;
        int oc = lane & 15, dy = (lane >> 4) & 1, rr = lane >> 5;
        int ky = ch * 2 + rr - dy;
        float w = 0.f;
        if (e < 6 && ky >= 0 && ky <= 4) w = Wfull[(oc * 6 + e) * 25 + ky * 5 + kx];
        _Float16 hw = (_Float16)w;
        AF[i] = __builtin_bit_cast(unsigned short, hw);
    }
    if (tid < 6)        bias[tid] = b3[tid];
    else if (tid < 15)  bias[tid] = b4[tid - 6];
    else if (tid == 15) bias[tid] = b6[0];
}

__global__ __launch_bounds__(256) void conv_mfma(
        const float* __restrict__ x, const unsigned short* __restrict__ AF,
        const float* __restrict__ bias, float* __restrict__ out) {
    __shared__ uint4 T4[TC * TR];   // 44352 B -> 3 blocks/CU

    const int tid = threadIdx.x;
    const int gx0 = blockIdx.x * BX;
    const int oy0 = blockIdx.y * BY;
    const int bz  = blockIdx.z;
    const float* xb = x + (size_t)bz * 6 * 512 * 512;

    // ---- stage: word (c*TR*4 + rr*4 + ip) = f16 pair (ic=2ip,2ip+1) at (c,rr)
    unsigned int* Tw = (unsigned int*)T4;
    for (int idx = tid; idx < TC * TR * 4; idx += 256) {
        int c  = idx % TC;
        int rr = (idx / TC) % TR;
        int ip = idx / (TC * TR);      // 0..3 -> ic pair (2ip, 2ip+1)
        int waddr = c * (TR * 4) + rr * 4 + ip;
        unsigned int val = 0u;
        int gy = oy0 + rr, gx = gx0 + c;
        if (ip < 3 && rr < 20 && gy < 512 && gx < 512) {
            const float* p0 = xb + ((size_t)(2 * ip) * 512 + gy) * 512 + gx;
            float v0 = p0[0];
            float v1 = p0[262144];     // next ic plane
            h2 h; h.x = (_Float16)v0; h.y = (_Float16)v1;
            val = __builtin_bit_cast(unsigned int, h);
        }
        Tw[waddr] = val;
    }
    __syncthreads();

    const int lane = tid & 63;
    const int n = lane & 31;        // B column = px within 32-strip
    const int h = lane >> 5;        // K half (within-chunk row)

    // A-fragments: 15 x 16 B per lane, coalesced, L2-resident
    h8 afr[15];
    #pragma unroll
    for (int q = 0; q < 15; ++q)
        afr[q] = *reinterpret_cast<const h8*>(AF + (q * 64 + lane) * 8);

    // bias init per acc reg: dy = reg>>3, oc = (reg&3) + 8*((reg>>2)&1) + 4*h
    f32x16 binit;
    #pragma unroll
    for (int reg = 0; reg < 16; ++reg)
        binit[reg] = bias[((reg & 3) + 8 * ((reg >> 2) & 1) + 4 * h) & 15];

    const int wv   = tid >> 6;                    // 0..3
    const int col0 = wv * 32;
    const int px   = gx0 + col0 + n;              // output x
    const uint4* Tb = &T4[(col0 + n) * TR + h];   // per-lane base (slot h)

    const size_t cs = (size_t)OW * OW;
    const bool px_ok = (px < OW);
    float* ob = out + ((size_t)bz * 16 + 4 * h) * cs + px;   // oc = ocb + 4h

    #pragma unroll 1
    for (int d = 0; d < BY; d += 2) {
        f32x16 acc = binit;
        #pragma unroll
        for (int kx = 0; kx < 5; ++kx) {
            #pragma unroll
            for (int ch = 0; ch < 3; ++ch) {
                h8 b = *reinterpret_cast<const h8*>(&Tb[kx * TR + d + ch * 2]);
                acc = __builtin_amdgcn_mfma_f32_32x32x16_f16(afr[kx * 3 + ch], b, acc, 0, 0, 0);
            }
        }
        #pragma unroll
        for (int dy = 0; dy < 2; ++dy) {
            const int oy = oy0 + d + dy;
            if (oy < OW && px_ok) {
                #pragma unroll
                for (int reg8 = 0; reg8 < 8; ++reg8) {
                    const int reg = dy * 8 + reg8;
                    const int ocb = (reg & 3) + 8 * ((reg >> 2) & 1);
                    ob[(size_t)ocb * cs + (size_t)oy * OW] = acc[reg];
                }
            }
        }
    }
}

extern "C" void kernel_launch(void* const* d_in, const int* in_sizes, int n_in,
                              void* d_out, int out_size, void* d_ws, size_t ws_size,
                              hipStream_t stream) {
    const float* x  = (const float*)d_in[0];
    const float* w3 = (const float*)d_in[1];
    const float* b3 = (const float*)d_in[2];
    const float* w4 = (const float*)d_in[3];
    const float* b4 = (const float*)d_in[4];
    const float* w6 = (const float*)d_in[5];
    const float* b6 = (const float*)d_in[6];
    float* out = (float*)d_out;

    float* bias        = (float*)d_ws;                    // 16 f32
    unsigned short* AF = (unsigned short*)(bias + 16);    // 7680 u16

    prep_weights<<<1, 256, 0, stream>>>(w3, b3, w4, b4, w6, b6, bias, AF);

    dim3 grid((OW + BX - 1) / BX, (OW + BY - 1) / BY, 32);  // 4, 32, 32
    conv_mfma<<<grid, 256, 0, stream>>>(x, AF, bias, out);
}